// Round 1
// baseline (66.299 us; speedup 1.0000x reference)
//
#include <hip/hip_runtime.h>
#include <math.h>

#define B 16
#define K 17
#define H 256
#define W 256
#define N 4
#define HW (H * W)

// One pixel per thread. Block = 256 threads; 256 blocks per batch image.
__global__ __launch_bounds__(256) void conseg_kernel(
    const float* __restrict__ masks,       // (B,1,H,W)
    const float* __restrict__ pred_flows,  // (N,B,2,H,W)
    const int* __restrict__ skls,          // (B,K,2)
    const float* __restrict__ flows,       // (B,2,H,W)
    float* __restrict__ out)               // [0]=loss, [1..]=mask_gt (B,1,H,W)
{
#pragma clang fp contract(off)
    __shared__ int   sx[K], sy[K];
    __shared__ float kfx[K], kfy[K], knrm[K];

    const int b   = blockIdx.x >> 8;          // 256 blocks per image
    const int tid = threadIdx.x;

    if (tid < K) {
        const int x = skls[(b * K + tid) * 2 + 0];
        const int y = skls[(b * K + tid) * 2 + 1];
        sx[tid] = x;
        sy[tid] = y;
        const float fx = flows[((b * 2 + 0) * H + y) * W + x];
        const float fy = flows[((b * 2 + 1) * H + y) * W + x];
        kfx[tid]  = fx;
        kfy[tid]  = fy;
        knrm[tid] = sqrtf(fx * fx + fy * fy);
    }
    __syncthreads();

    const int pix = ((blockIdx.x & 255) << 8) + tid;   // 0..HW-1
    const int h   = pix >> 8;                          // W == 256
    const int w   = pix & 255;

    // argmin over K keypoints (exact integer distances, first-min tie-break)
    int best  = 0;
    int bestd = 0x7fffffff;
#pragma unroll
    for (int k = 0; k < K; ++k) {
        const int dx = w - sx[k];
        const int dy = h - sy[k];
        const int d  = dx * dx + dy * dy;
        if (d < bestd) { bestd = d; best = k; }
    }

    const float kx  = kfx[best];
    const float ky  = kfy[best];
    const float knv = knrm[best];

    const float x  = masks[b * HW + pix];
    // max(x,0) + softplus(-|x|) is the same for all N iterations
    const float sp = fmaxf(x, 0.0f) + log1pf(expf(-fabsf(x)));

    // weights = 0.8^(N-1-i)
    const float wts[N] = {0.512f, 0.64f, 0.8f, 1.0f};
    float acc = (0.512f + 0.64f + 0.8f + 1.0f) * sp;

    const size_t base = (size_t)b * 2 * HW + pix;
    float zlast = 0.0f;
#pragma unroll
    for (int i = 0; i < N; ++i) {
        const float px  = pred_flows[(size_t)i * B * 2 * HW + base];
        const float py  = pred_flows[(size_t)i * B * 2 * HW + base + HW];
        const float dot = px * kx + py * ky;
        const float pn  = sqrtf(px * px + py * py);
        const float sim = dot / (pn * knv + 1e-6f);
        const float z   = (sim > 0.95f) ? 1.0f : 0.0f;
        acc -= wts[i] * (x * z);
        zlast = z;
    }

    out[1 + (size_t)b * HW + pix] = zlast;

    // block reduction of acc -> one atomicAdd per block
    for (int off = 32; off > 0; off >>= 1)
        acc += __shfl_down(acc, off, 64);

    __shared__ float wsum[4];
    if ((tid & 63) == 0) wsum[tid >> 6] = acc;
    __syncthreads();
    if (tid == 0) {
        const float s = wsum[0] + wsum[1] + wsum[2] + wsum[3];
        atomicAdd(out, s * (1.0f / (float)(B * HW)));
    }
}

extern "C" void kernel_launch(void* const* d_in, const int* in_sizes, int n_in,
                              void* d_out, int out_size, void* d_ws, size_t ws_size,
                              hipStream_t stream) {
    const float* masks      = (const float*)d_in[0];
    const float* pred_flows = (const float*)d_in[1];
    const int*   skls       = (const int*)d_in[2];
    const float* flows      = (const float*)d_in[3];
    float* out = (float*)d_out;

    // zero the loss accumulator (capture-safe)
    hipMemsetAsync(out, 0, sizeof(float), stream);

    const int blocks = B * (HW / 256);  // 4096
    conseg_kernel<<<blocks, 256, 0, stream>>>(masks, pred_flows, skls, flows, out);
}

// Round 2
// 31.308 us; speedup vs baseline: 2.1177x; 2.1177x over previous
//
#include <hip/hip_runtime.h>
#include <math.h>

#define B 16
#define K 17
#define H 256
#define W 256
#define N 4
#define HW (H * W)
#define PPT 4                      // pixels per thread (float4)

// Each thread: 4 consecutive pixels (same row). Block = 256 threads -> 1024 px.
__global__ __launch_bounds__(256) void conseg_kernel(
    const float* __restrict__ masks,       // (B,1,H,W)
    const float* __restrict__ pred_flows,  // (N,B,2,H,W)
    const int* __restrict__ skls,          // (B,K,2)
    const float* __restrict__ flows,       // (B,2,H,W)
    float* __restrict__ out)               // [0]=loss, [1..]=mask_gt (B,1,H,W)
{
#pragma clang fp contract(off)
    __shared__ int   sx[K], sy[K];
    __shared__ float kfx[K], kfy[K], knrm[K];

    const int b   = blockIdx.x >> 6;          // 64 blocks per image
    const int tid = threadIdx.x;

    if (tid < K) {
        const int x = skls[(b * K + tid) * 2 + 0];
        const int y = skls[(b * K + tid) * 2 + 1];
        sx[tid] = x;
        sy[tid] = y;
        const float fx = flows[((b * 2 + 0) * H + y) * W + x];
        const float fy = flows[((b * 2 + 1) * H + y) * W + x];
        kfx[tid]  = fx;
        kfy[tid]  = fy;
        knrm[tid] = sqrtf(fx * fx + fy * fy);
    }
    __syncthreads();

    const int pix0 = ((blockIdx.x & 63) << 10) + tid * PPT;  // first of 4 px
    const int h    = pix0 >> 8;                              // same row for all 4
    const int w0   = pix0 & 255;

    // ---- issue all global loads up front (ILP) ----
    const float4 xm = *(const float4*)(masks + (size_t)b * HW + pix0);

    const size_t base = (size_t)b * 2 * HW + pix0;
    float4 px[N], py[N];
#pragma unroll
    for (int i = 0; i < N; ++i) {
        px[i] = *(const float4*)(pred_flows + (size_t)i * B * 2 * HW + base);
        py[i] = *(const float4*)(pred_flows + (size_t)i * B * 2 * HW + base + HW);
    }

    // ---- argmin over K keypoints for each of the 4 pixels ----
    int best[PPT];
    int bestd[PPT];
#pragma unroll
    for (int j = 0; j < PPT; ++j) { best[j] = 0; bestd[j] = 0x7fffffff; }
#pragma unroll
    for (int k = 0; k < K; ++k) {
        const int kx = sx[k];
        const int dy = h - sy[k];
        const int dyy = dy * dy;
#pragma unroll
        for (int j = 0; j < PPT; ++j) {
            const int dx = (w0 + j) - kx;
            const int d  = dx * dx + dyy;
            if (d < bestd[j]) { bestd[j] = d; best[j] = k; }
        }
    }

    const float wts[N] = {0.512f, 0.64f, 0.8f, 1.0f};
    const float wsumc  = 0.512f + 0.64f + 0.8f + 1.0f;

    float acc = 0.0f;
    float zout[PPT];
#pragma unroll
    for (int j = 0; j < PPT; ++j) {
        const float kx  = kfx[best[j]];
        const float ky  = kfy[best[j]];
        const float knv = knrm[best[j]];

        const float x  = ((const float*)&xm)[j];
        const float sp = fmaxf(x, 0.0f) + log1pf(expf(-fabsf(x)));
        acc += wsumc * sp;

        float zlast = 0.0f;
#pragma unroll
        for (int i = 0; i < N; ++i) {
            const float pxv = ((const float*)&px[i])[j];
            const float pyv = ((const float*)&py[i])[j];
            const float dot = pxv * kx + pyv * ky;
            const float pn  = sqrtf(pxv * pxv + pyv * pyv);
            const float sim = dot / (pn * knv + 1e-6f);
            const float z   = (sim > 0.95f) ? 1.0f : 0.0f;
            acc -= wts[i] * (x * z);
            zlast = z;
        }
        zout[j] = zlast;
    }

    // mask_gt store (out+1 is only 4B-aligned -> scalar stores)
    float* og = out + 1 + (size_t)b * HW + pix0;
#pragma unroll
    for (int j = 0; j < PPT; ++j) og[j] = zout[j];

    // block reduction of acc -> one atomicAdd per block
    for (int off = 32; off > 0; off >>= 1)
        acc += __shfl_down(acc, off, 64);

    __shared__ float wsum[4];
    if ((tid & 63) == 0) wsum[tid >> 6] = acc;
    __syncthreads();
    if (tid == 0) {
        const float s = wsum[0] + wsum[1] + wsum[2] + wsum[3];
        atomicAdd(out, s * (1.0f / (float)(B * HW)));
    }
}

extern "C" void kernel_launch(void* const* d_in, const int* in_sizes, int n_in,
                              void* d_out, int out_size, void* d_ws, size_t ws_size,
                              hipStream_t stream) {
    const float* masks      = (const float*)d_in[0];
    const float* pred_flows = (const float*)d_in[1];
    const int*   skls       = (const int*)d_in[2];
    const float* flows      = (const float*)d_in[3];
    float* out = (float*)d_out;

    hipMemsetAsync(out, 0, sizeof(float), stream);

    const int blocks = B * (HW / (256 * PPT));  // 1024
    conseg_kernel<<<blocks, 256, 0, stream>>>(masks, pred_flows, skls, flows, out);
}

// Round 3
// 20.057 us; speedup vs baseline: 3.3056x; 1.5610x over previous
//
#include <hip/hip_runtime.h>
#include <math.h>

#define B 16
#define K 17
#define H 256
#define W 256
#define N 4
#define HW (H * W)
#define PPT 4                      // pixels per thread (float4)
#define NBLK (B * (HW / (256 * PPT)))   // 1024 blocks

// Each thread: 4 consecutive pixels (same row). Block = 256 threads -> 1024 px.
__global__ __launch_bounds__(256) void conseg_kernel(
    const float* __restrict__ masks,       // (B,1,H,W)
    const float* __restrict__ pred_flows,  // (N,B,2,H,W)
    const int* __restrict__ skls,          // (B,K,2)
    const float* __restrict__ flows,       // (B,2,H,W)
    float* __restrict__ out,               // [0]=loss, [1..]=mask_gt (B,1,H,W)
    float* __restrict__ partials)          // d_ws: one float per block
{
#pragma clang fp contract(off)
    __shared__ int   sx[K], sy[K];
    __shared__ float kfx[K], kfy[K], knrm[K];

    const int b   = blockIdx.x >> 6;          // 64 blocks per image
    const int tid = threadIdx.x;

    if (tid < K) {
        const int x = skls[(b * K + tid) * 2 + 0];
        const int y = skls[(b * K + tid) * 2 + 1];
        sx[tid] = x;
        sy[tid] = y;
        const float fx = flows[((b * 2 + 0) * H + y) * W + x];
        const float fy = flows[((b * 2 + 1) * H + y) * W + x];
        kfx[tid]  = fx;
        kfy[tid]  = fy;
        knrm[tid] = sqrtf(fx * fx + fy * fy);
    }
    __syncthreads();

    const int pix0 = ((blockIdx.x & 63) << 10) + tid * PPT;  // first of 4 px
    const int h    = pix0 >> 8;                              // same row for all 4
    const int w0   = pix0 & 255;

    // ---- issue all global loads up front (ILP) ----
    const float4 xm = *(const float4*)(masks + (size_t)b * HW + pix0);

    const size_t base = (size_t)b * 2 * HW + pix0;
    float4 px[N], py[N];
#pragma unroll
    for (int i = 0; i < N; ++i) {
        px[i] = *(const float4*)(pred_flows + (size_t)i * B * 2 * HW + base);
        py[i] = *(const float4*)(pred_flows + (size_t)i * B * 2 * HW + base + HW);
    }

    // ---- argmin over K keypoints for each of the 4 pixels ----
    int best[PPT];
    int bestd[PPT];
#pragma unroll
    for (int j = 0; j < PPT; ++j) { best[j] = 0; bestd[j] = 0x7fffffff; }
#pragma unroll
    for (int k = 0; k < K; ++k) {
        const int kx = sx[k];
        const int dy = h - sy[k];
        const int dyy = dy * dy;
#pragma unroll
        for (int j = 0; j < PPT; ++j) {
            const int dx = (w0 + j) - kx;
            const int d  = dx * dx + dyy;
            if (d < bestd[j]) { bestd[j] = d; best[j] = k; }
        }
    }

    const float wts[N] = {0.512f, 0.64f, 0.8f, 1.0f};
    const float wsumc  = 0.512f + 0.64f + 0.8f + 1.0f;

    float acc = 0.0f;
    float zout[PPT];
#pragma unroll
    for (int j = 0; j < PPT; ++j) {
        const float kx  = kfx[best[j]];
        const float ky  = kfy[best[j]];
        const float knv = knrm[best[j]];

        const float x  = ((const float*)&xm)[j];
        const float sp = fmaxf(x, 0.0f) + log1pf(expf(-fabsf(x)));
        acc += wsumc * sp;

        float zlast = 0.0f;
#pragma unroll
        for (int i = 0; i < N; ++i) {
            const float pxv = ((const float*)&px[i])[j];
            const float pyv = ((const float*)&py[i])[j];
            const float dot = pxv * kx + pyv * ky;
            const float pn  = sqrtf(pxv * pxv + pyv * pyv);
            const float sim = dot / (pn * knv + 1e-6f);
            const float z   = (sim > 0.95f) ? 1.0f : 0.0f;
            acc -= wts[i] * (x * z);
            zlast = z;
        }
        zout[j] = zlast;
    }

    // mask_gt store (out+1 is only 4B-aligned -> scalar stores)
    float* og = out + 1 + (size_t)b * HW + pix0;
#pragma unroll
    for (int j = 0; j < PPT; ++j) og[j] = zout[j];

    // block reduction of acc -> ONE plain store per block (no atomics)
    for (int off = 32; off > 0; off >>= 1)
        acc += __shfl_down(acc, off, 64);

    __shared__ float wsum[4];
    if ((tid & 63) == 0) wsum[tid >> 6] = acc;
    __syncthreads();
    if (tid == 0)
        partials[blockIdx.x] = wsum[0] + wsum[1] + wsum[2] + wsum[3];
}

// Single-wave final reduction: 1024 partials -> out[0]
__global__ __launch_bounds__(64) void conseg_reduce(
    const float* __restrict__ partials, float* __restrict__ out)
{
    const int tid = threadIdx.x;
    float s = 0.0f;
#pragma unroll
    for (int i = 0; i < NBLK / 64; ++i)
        s += partials[tid + i * 64];
    for (int off = 32; off > 0; off >>= 1)
        s += __shfl_down(s, off, 64);
    if (tid == 0)
        out[0] = s * (1.0f / (float)(B * HW));
}

extern "C" void kernel_launch(void* const* d_in, const int* in_sizes, int n_in,
                              void* d_out, int out_size, void* d_ws, size_t ws_size,
                              hipStream_t stream) {
    const float* masks      = (const float*)d_in[0];
    const float* pred_flows = (const float*)d_in[1];
    const int*   skls       = (const int*)d_in[2];
    const float* flows      = (const float*)d_in[3];
    float* out      = (float*)d_out;
    float* partials = (float*)d_ws;

    conseg_kernel<<<NBLK, 256, 0, stream>>>(masks, pred_flows, skls, flows, out, partials);
    conseg_reduce<<<1, 64, 0, stream>>>(partials, out);
}

// Round 4
// 18.248 us; speedup vs baseline: 3.6332x; 1.0991x over previous
//
#include <hip/hip_runtime.h>
#include <math.h>

#define B 16
#define K 17
#define H 256
#define W 256
#define N 4
#define HW (H * W)
#define PPT 2                           // pixels per thread (float2)
#define NBLK (B * (HW / (256 * PPT)))   // 2048 blocks -> 8192 waves = 100% occ

// Each thread: 2 consecutive pixels (same row). Block = 256 threads -> 512 px.
__global__ __launch_bounds__(256) void conseg_kernel(
    const float* __restrict__ masks,       // (B,1,H,W)
    const float* __restrict__ pred_flows,  // (N,B,2,H,W)
    const int* __restrict__ skls,          // (B,K,2)
    const float* __restrict__ flows,       // (B,2,H,W)
    float* __restrict__ out,               // [0]=loss, [1..]=mask_gt (B,1,H,W)
    float* __restrict__ partials)          // d_ws: one float per block
{
#pragma clang fp contract(off)
    __shared__ int   sx[K], sy[K];
    __shared__ float kfx[K], kfy[K], knrm[K];

    const int b   = blockIdx.x >> 7;          // 128 blocks per image
    const int tid = threadIdx.x;

    if (tid < K) {
        const int x = skls[(b * K + tid) * 2 + 0];
        const int y = skls[(b * K + tid) * 2 + 1];
        sx[tid] = x;
        sy[tid] = y;
        const float fx = flows[((b * 2 + 0) * H + y) * W + x];
        const float fy = flows[((b * 2 + 1) * H + y) * W + x];
        kfx[tid]  = fx;
        kfy[tid]  = fy;
        knrm[tid] = sqrtf(fx * fx + fy * fy);
    }
    __syncthreads();

    const int pix0 = ((blockIdx.x & 127) << 9) + tid * PPT;  // first of 2 px
    const int h    = pix0 >> 8;                              // same row for both
    const int w0   = pix0 & 255;

    // ---- issue all global loads up front (ILP) ----
    const float2 xm = *(const float2*)(masks + (size_t)b * HW + pix0);

    const size_t base = (size_t)b * 2 * HW + pix0;
    float2 px[N], py[N];
#pragma unroll
    for (int i = 0; i < N; ++i) {
        px[i] = *(const float2*)(pred_flows + (size_t)i * B * 2 * HW + base);
        py[i] = *(const float2*)(pred_flows + (size_t)i * B * 2 * HW + base + HW);
    }

    // ---- argmin over K keypoints for each pixel ----
    int best[PPT];
    int bestd[PPT];
#pragma unroll
    for (int j = 0; j < PPT; ++j) { best[j] = 0; bestd[j] = 0x7fffffff; }
#pragma unroll
    for (int k = 0; k < K; ++k) {
        const int kx = sx[k];
        const int dy = h - sy[k];
        const int dyy = dy * dy;
#pragma unroll
        for (int j = 0; j < PPT; ++j) {
            const int dx = (w0 + j) - kx;
            const int d  = dx * dx + dyy;
            if (d < bestd[j]) { bestd[j] = d; best[j] = k; }
        }
    }

    const float wts[N] = {0.512f, 0.64f, 0.8f, 1.0f};
    const float wsumc  = 0.512f + 0.64f + 0.8f + 1.0f;

    float acc = 0.0f;
    float zout[PPT];
#pragma unroll
    for (int j = 0; j < PPT; ++j) {
        const float kx  = kfx[best[j]];
        const float ky  = kfy[best[j]];
        const float knv = knrm[best[j]];

        const float x  = ((const float*)&xm)[j];
        const float sp = fmaxf(x, 0.0f) + log1pf(expf(-fabsf(x)));
        acc += wsumc * sp;

        float zlast = 0.0f;
#pragma unroll
        for (int i = 0; i < N; ++i) {
            const float pxv = ((const float*)&px[i])[j];
            const float pyv = ((const float*)&py[i])[j];
            const float dot = pxv * kx + pyv * ky;
            const float pn  = sqrtf(pxv * pxv + pyv * pyv);
            const float sim = dot / (pn * knv + 1e-6f);
            const float z   = (sim > 0.95f) ? 1.0f : 0.0f;
            acc -= wts[i] * (x * z);
            zlast = z;
        }
        zout[j] = zlast;
    }

    // mask_gt store (out+1 is only 4B-aligned -> scalar, nontemporal)
    float* og = out + 1 + (size_t)b * HW + pix0;
#pragma unroll
    for (int j = 0; j < PPT; ++j) __builtin_nontemporal_store(zout[j], og + j);

    // block reduction of acc -> ONE plain store per block (no atomics)
    for (int off = 32; off > 0; off >>= 1)
        acc += __shfl_down(acc, off, 64);

    __shared__ float wsum[4];
    if ((tid & 63) == 0) wsum[tid >> 6] = acc;
    __syncthreads();
    if (tid == 0)
        partials[blockIdx.x] = wsum[0] + wsum[1] + wsum[2] + wsum[3];
}

// Final reduction: NBLK partials -> out[0]. One 256-thread block.
__global__ __launch_bounds__(256) void conseg_reduce(
    const float* __restrict__ partials, float* __restrict__ out)
{
    const int tid = threadIdx.x;
    float s = 0.0f;
#pragma unroll
    for (int i = 0; i < NBLK / 256; ++i)
        s += partials[tid + i * 256];
    for (int off = 32; off > 0; off >>= 1)
        s += __shfl_down(s, off, 64);

    __shared__ float wsum[4];
    if ((tid & 63) == 0) wsum[tid >> 6] = s;
    __syncthreads();
    if (tid == 0)
        out[0] = (wsum[0] + wsum[1] + wsum[2] + wsum[3]) * (1.0f / (float)(B * HW));
}

extern "C" void kernel_launch(void* const* d_in, const int* in_sizes, int n_in,
                              void* d_out, int out_size, void* d_ws, size_t ws_size,
                              hipStream_t stream) {
    const float* masks      = (const float*)d_in[0];
    const float* pred_flows = (const float*)d_in[1];
    const int*   skls       = (const int*)d_in[2];
    const float* flows      = (const float*)d_in[3];
    float* out      = (float*)d_out;
    float* partials = (float*)d_ws;

    conseg_kernel<<<NBLK, 256, 0, stream>>>(masks, pred_flows, skls, flows, out, partials);
    conseg_reduce<<<1, 256, 0, stream>>>(partials, out);
}

// Round 5
// 16.806 us; speedup vs baseline: 3.9449x; 1.0858x over previous
//
#include <hip/hip_runtime.h>
#include <math.h>

#define B 16
#define K 17
#define H 256
#define W 256
#define N 4
#define HW (H * W)
#define PPT 2                           // pixels per thread (float2)
#define NBLK (B * (HW / (256 * PPT)))   // 2048 blocks -> 8192 waves = 100% occ

// Each thread: 2 consecutive pixels (same row). Block = 256 threads -> 512 px.
__global__ __launch_bounds__(256) void conseg_kernel(
    const float* __restrict__ masks,       // (B,1,H,W)
    const float* __restrict__ pred_flows,  // (N,B,2,H,W)
    const int* __restrict__ skls,          // (B,K,2)
    const float* __restrict__ flows,       // (B,2,H,W)
    float* __restrict__ out,               // [0]=loss, [1..]=mask_gt (B,1,H,W)
    float* __restrict__ partials)          // d_ws: one float per block
{
#pragma clang fp contract(off)
    const int b    = blockIdx.x >> 7;         // 128 blocks per image (uniform)
    const int tid  = threadIdx.x;
    const int lane = tid & 63;

    // ---- per-wave keypoint flow: lane k (k<17) holds flow at keypoint k ----
    const int  lk  = min(lane, K - 1);
    const int2 kpl = ((const int2*)skls)[b * K + lk];
    const float kfx = flows[((size_t)(b * 2 + 0) * H + kpl.y) * W + kpl.x];
    const float kfy = flows[((size_t)(b * 2 + 1) * H + kpl.y) * W + kpl.x];
    const float kkn = sqrtf(kfx * kfx + kfy * kfy);

    const int pix0 = ((blockIdx.x & 127) << 9) + tid * PPT;
    const int h    = pix0 >> 8;
    const int w0   = pix0 & 255;

    // ---- issue all bulk global loads up front (ILP) ----
    const float2 xm = *(const float2*)(masks + (size_t)b * HW + pix0);
    const size_t base = (size_t)b * 2 * HW + pix0;
    float2 px[N], py[N];
#pragma unroll
    for (int i = 0; i < N; ++i) {
        px[i] = *(const float2*)(pred_flows + (size_t)i * B * 2 * HW + base);
        py[i] = *(const float2*)(pred_flows + (size_t)i * B * 2 * HW + base + HW);
    }

    // ---- keypoint coords via wave-uniform (scalar) loads ----
    int2 kp[K];
#pragma unroll
    for (int k = 0; k < K; ++k) kp[k] = ((const int2*)skls)[b * K + k];

    // ---- packed argmin: min over (d<<5 | k); d < 2^17 exact, ties -> min k ----
    int best0 = 0x7fffffff, best1 = 0x7fffffff;
#pragma unroll
    for (int k = 0; k < K; ++k) {
        const int dy  = h - kp[k].y;
        const int dyy = dy * dy;
        const int dx0 = w0 - kp[k].x;
        const int dx1 = dx0 + 1;
        const int d0  = dx0 * dx0 + dyy;
        const int d1  = dx1 * dx1 + dyy;
        best0 = min(best0, (d0 << 5) | k);
        best1 = min(best1, (d1 << 5) | k);
    }
    const int k0 = best0 & 31;
    const int k1 = best1 & 31;

    // ---- gather selected keypoint flow via cross-lane shuffle (no LDS) ----
    const float kx0 = __shfl(kfx, k0), ky0 = __shfl(kfy, k0), kn0 = __shfl(kkn, k0);
    const float kx1 = __shfl(kfx, k1), ky1 = __shfl(kfy, k1), kn1 = __shfl(kkn, k1);

    const float wts[N] = {0.512f, 0.64f, 0.8f, 1.0f};
    float acc = 0.0f;
    float z0 = 0.0f, z1 = 0.0f;

    {   // pixel 0
        const float x  = xm.x;
        const float sp = fmaxf(x, 0.0f) + __logf(1.0f + __expf(-fabsf(x)));
        acc += 2.952f * sp;
#pragma unroll
        for (int i = 0; i < N; ++i) {
            const float pxv = px[i].x, pyv = py[i].x;
            const float dot = pxv * kx0 + pyv * ky0;
            const float pn  = sqrtf(pxv * pxv + pyv * pyv);
            const float sim = dot / (pn * kn0 + 1e-6f);
            const float z   = (sim > 0.95f) ? 1.0f : 0.0f;
            acc -= wts[i] * (x * z);
            z0 = z;
        }
    }
    {   // pixel 1
        const float x  = xm.y;
        const float sp = fmaxf(x, 0.0f) + __logf(1.0f + __expf(-fabsf(x)));
        acc += 2.952f * sp;
#pragma unroll
        for (int i = 0; i < N; ++i) {
            const float pxv = px[i].y, pyv = py[i].y;
            const float dot = pxv * kx1 + pyv * ky1;
            const float pn  = sqrtf(pxv * pxv + pyv * pyv);
            const float sim = dot / (pn * kn1 + 1e-6f);
            const float z   = (sim > 0.95f) ? 1.0f : 0.0f;
            acc -= wts[i] * (x * z);
            z1 = z;
        }
    }

    // mask_gt store (out+1 is only 4B-aligned -> scalar, nontemporal)
    float* og = out + 1 + (size_t)b * HW + pix0;
    __builtin_nontemporal_store(z0, og + 0);
    __builtin_nontemporal_store(z1, og + 1);

    // block reduction of acc -> ONE plain store per block (no atomics)
    for (int off = 32; off > 0; off >>= 1)
        acc += __shfl_down(acc, off, 64);

    __shared__ float wsum[4];
    if ((tid & 63) == 0) wsum[tid >> 6] = acc;
    __syncthreads();
    if (tid == 0)
        partials[blockIdx.x] = wsum[0] + wsum[1] + wsum[2] + wsum[3];
}

// Final reduction: NBLK partials -> out[0]. One 256-thread block.
__global__ __launch_bounds__(256) void conseg_reduce(
    const float* __restrict__ partials, float* __restrict__ out)
{
    const int tid = threadIdx.x;
    float s = 0.0f;
#pragma unroll
    for (int i = 0; i < NBLK / 256; ++i)
        s += partials[tid + i * 256];
    for (int off = 32; off > 0; off >>= 1)
        s += __shfl_down(s, off, 64);

    __shared__ float wsum[4];
    if ((tid & 63) == 0) wsum[tid >> 6] = s;
    __syncthreads();
    if (tid == 0)
        out[0] = (wsum[0] + wsum[1] + wsum[2] + wsum[3]) * (1.0f / (float)(B * HW));
}

extern "C" void kernel_launch(void* const* d_in, const int* in_sizes, int n_in,
                              void* d_out, int out_size, void* d_ws, size_t ws_size,
                              hipStream_t stream) {
    const float* masks      = (const float*)d_in[0];
    const float* pred_flows = (const float*)d_in[1];
    const int*   skls       = (const int*)d_in[2];
    const float* flows      = (const float*)d_in[3];
    float* out      = (float*)d_out;
    float* partials = (float*)d_ws;

    conseg_kernel<<<NBLK, 256, 0, stream>>>(masks, pred_flows, skls, flows, out, partials);
    conseg_reduce<<<1, 256, 0, stream>>>(partials, out);
}

// Round 6
// 16.269 us; speedup vs baseline: 4.0752x; 1.0330x over previous
//
#include <hip/hip_runtime.h>
#include <math.h>

#define B 16
#define K 17
#define H 256
#define W 256
#define N 4
#define HW (H * W)
#define PPT 2                           // pixels per thread (float2)
#define NBLK (B * (HW / (256 * PPT)))   // 2048 blocks -> 8192 waves = 100% occ
#define NPART (NBLK * 4)                // one partial per wave

// Each thread: 2 consecutive pixels (same row). Block = 256 threads -> 512 px.
__global__ __launch_bounds__(256) void conseg_kernel(
    const float* __restrict__ masks,       // (B,1,H,W)
    const float* __restrict__ pred_flows,  // (N,B,2,H,W)
    const int* __restrict__ skls,          // (B,K,2)
    const float* __restrict__ flows,       // (B,2,H,W)
    float* __restrict__ out,               // [0]=loss, [1..]=mask_gt (B,1,H,W)
    float* __restrict__ partials)          // d_ws: one float per wave
{
#pragma clang fp contract(off)
    const int b    = blockIdx.x >> 7;         // 128 blocks per image (uniform)
    const int tid  = threadIdx.x;
    const int lane = tid & 63;

    // ---- per-wave keypoint flow: lane k (k<17) holds flow at keypoint k ----
    const int  lk  = min(lane, K - 1);
    const int2 kpl = ((const int2*)skls)[b * K + lk];
    const float kfx = flows[((size_t)(b * 2 + 0) * H + kpl.y) * W + kpl.x];
    const float kfy = flows[((size_t)(b * 2 + 1) * H + kpl.y) * W + kpl.x];
    const float kkn = sqrtf(kfx * kfx + kfy * kfy);   // exact (feeds i=3 path)

    const int pix0 = ((blockIdx.x & 127) << 9) + tid * PPT;
    const int h    = pix0 >> 8;
    const int w0   = pix0 & 255;

    // ---- issue all bulk global loads up front (ILP) ----
    const float2 xm = *(const float2*)(masks + (size_t)b * HW + pix0);
    const size_t base = (size_t)b * 2 * HW + pix0;
    float2 px[N], py[N];
#pragma unroll
    for (int i = 0; i < N; ++i) {
        px[i] = *(const float2*)(pred_flows + (size_t)i * B * 2 * HW + base);
        py[i] = *(const float2*)(pred_flows + (size_t)i * B * 2 * HW + base + HW);
    }

    // ---- keypoint coords via wave-uniform (scalar) loads ----
    int2 kp[K];
#pragma unroll
    for (int k = 0; k < K; ++k) kp[k] = ((const int2*)skls)[b * K + k];

    // ---- packed argmin: min over (d<<5 | k); d < 2^17 exact, ties -> min k ----
    int best0 = 0x7fffffff, best1 = 0x7fffffff;
#pragma unroll
    for (int k = 0; k < K; ++k) {
        const int dy  = h - kp[k].y;
        const int dyy = dy * dy;
        const int dx0 = w0 - kp[k].x;
        const int dx1 = dx0 + 1;
        const int d0  = dx0 * dx0 + dyy;
        const int d1  = dx1 * dx1 + dyy;
        best0 = min(best0, (d0 << 5) | k);
        best1 = min(best1, (d1 << 5) | k);
    }
    const int k0 = best0 & 31;
    const int k1 = best1 & 31;

    // ---- gather selected keypoint flow via cross-lane shuffle (no LDS) ----
    const float kx0 = __shfl(kfx, k0), ky0 = __shfl(kfy, k0), kn0 = __shfl(kkn, k0);
    const float kx1 = __shfl(kfx, k1), ky1 = __shfl(kfy, k1), kn1 = __shfl(kkn, k1);

    float acc = 0.0f;
    float z0 = 0.0f, z1 = 0.0f;

    {   // pixel 0
        const float x  = xm.x;
        const float sp = fmaxf(x, 0.0f) + __logf(1.0f + __expf(-fabsf(x)));
        acc += 2.952f * sp;
        // i = 0..2: loss-only -> fast math (a z-flip shifts loss by ~1e-6)
#pragma unroll
        for (int i = 0; i < 3; ++i) {
            const float pxv = px[i].x, pyv = py[i].x;
            const float dot = fmaf(pxv, kx0, pyv * ky0);
            const float pn  = __builtin_amdgcn_sqrtf(fmaf(pxv, pxv, pyv * pyv));
            const float thr = 0.95f * fmaf(pn, kn0, 1e-6f);
            const float wx  = (i == 0) ? 0.512f : (i == 1) ? 0.64f : 0.8f;
            if (dot > thr) acc -= wx * x;
        }
        // i = 3: feeds mask_gt -> bit-exact path (mul/add, IEEE sqrt, IEEE div)
        {
            const float pxv = px[3].x, pyv = py[3].x;
            const float dot = pxv * kx0 + pyv * ky0;
            const float pn  = sqrtf(pxv * pxv + pyv * pyv);
            const float sim = dot / (pn * kn0 + 1e-6f);
            const float z   = (sim > 0.95f) ? 1.0f : 0.0f;
            acc -= x * z;
            z0 = z;
        }
    }
    {   // pixel 1
        const float x  = xm.y;
        const float sp = fmaxf(x, 0.0f) + __logf(1.0f + __expf(-fabsf(x)));
        acc += 2.952f * sp;
#pragma unroll
        for (int i = 0; i < 3; ++i) {
            const float pxv = px[i].y, pyv = py[i].y;
            const float dot = fmaf(pxv, kx1, pyv * ky1);
            const float pn  = __builtin_amdgcn_sqrtf(fmaf(pxv, pxv, pyv * pyv));
            const float thr = 0.95f * fmaf(pn, kn1, 1e-6f);
            const float wx  = (i == 0) ? 0.512f : (i == 1) ? 0.64f : 0.8f;
            if (dot > thr) acc -= wx * x;
        }
        {
            const float pxv = px[3].y, pyv = py[3].y;
            const float dot = pxv * kx1 + pyv * ky1;
            const float pn  = sqrtf(pxv * pxv + pyv * pyv);
            const float sim = dot / (pn * kn1 + 1e-6f);
            const float z   = (sim > 0.95f) ? 1.0f : 0.0f;
            acc -= x * z;
            z1 = z;
        }
    }

    // mask_gt store (out+1 is only 4B-aligned -> scalar, nontemporal)
    float* og = out + 1 + (size_t)b * HW + pix0;
    __builtin_nontemporal_store(z0, og + 0);
    __builtin_nontemporal_store(z1, og + 1);

    // wave reduction of acc -> one plain store per wave (no LDS, no barrier)
    for (int off = 32; off > 0; off >>= 1)
        acc += __shfl_down(acc, off, 64);
    if (lane == 0)
        partials[blockIdx.x * 4 + (tid >> 6)] = acc;
}

// Final reduction: NPART partials -> out[0]. One 256-thread block.
__global__ __launch_bounds__(256) void conseg_reduce(
    const float* __restrict__ partials, float* __restrict__ out)
{
    const int tid = threadIdx.x;
    float s = 0.0f;
#pragma unroll
    for (int i = 0; i < NPART / 256; ++i)
        s += partials[tid + i * 256];
    for (int off = 32; off > 0; off >>= 1)
        s += __shfl_down(s, off, 64);

    __shared__ float wsum[4];
    if ((tid & 63) == 0) wsum[tid >> 6] = s;
    __syncthreads();
    if (tid == 0)
        out[0] = (wsum[0] + wsum[1] + wsum[2] + wsum[3]) * (1.0f / (float)(B * HW));
}

extern "C" void kernel_launch(void* const* d_in, const int* in_sizes, int n_in,
                              void* d_out, int out_size, void* d_ws, size_t ws_size,
                              hipStream_t stream) {
    const float* masks      = (const float*)d_in[0];
    const float* pred_flows = (const float*)d_in[1];
    const int*   skls       = (const int*)d_in[2];
    const float* flows      = (const float*)d_in[3];
    float* out      = (float*)d_out;
    float* partials = (float*)d_ws;

    conseg_kernel<<<NBLK, 256, 0, stream>>>(masks, pred_flows, skls, flows, out, partials);
    conseg_reduce<<<1, 256, 0, stream>>>(partials, out);
}